// Round 1
// baseline (751.413 us; speedup 1.0000x reference)
//
#include <hip/hip_runtime.h>
#include <hip/hip_bf16.h>
#include <stdint.h>

typedef __attribute__((ext_vector_type(8))) short bf16x8;
typedef __attribute__((ext_vector_type(4))) float f32x4;

#define Bn 16
#define Kn 16
#define Sn 512
#define En 512
#define Ln 16
#define Hn 8
#define Dn 64
#define MTOT (Bn*Kn*Sn)   // 131072 rows of spike

__device__ __forceinline__ float blo(uint32_t u){ return __uint_as_float(u << 16); }
__device__ __forceinline__ float bhi(uint32_t u){ return __uint_as_float(u & 0xffff0000u); }

// pack two f32 -> two bf16 (round-half-up via +0x8000, then take hi16 of each)
__device__ __forceinline__ uint32_t pack_bf16(float lo, float hi) {
  uint32_t a = __float_as_uint(lo) + 0x8000u;
  uint32_t b = __float_as_uint(hi) + 0x8000u;
  // result = [b.hi16 : a.hi16]  (low half = lo element)
  return __builtin_amdgcn_perm(b, a, 0x07060302u);
}

// ---------------- Kernel 0: xq = latent_query @ Wq^T  (16 x 512) ----------------
__global__ __launch_bounds__(256)
void xq_kernel(const float* __restrict__ latent, const float* __restrict__ Wq,
               float* __restrict__ xq)
{
  const int j = blockIdx.x;          // output column 0..511
  const int t = threadIdx.x;
  const float w0 = Wq[j*En + t];
  const float w1 = Wq[j*En + t + 256];
  float part[Ln];
#pragma unroll
  for (int l = 0; l < Ln; ++l)
    part[l] = w0 * latent[l*En + t] + w1 * latent[l*En + t + 256];
#pragma unroll
  for (int l = 0; l < Ln; ++l) {
    float v = part[l];
#pragma unroll
    for (int off = 32; off > 0; off >>= 1) v += __shfl_down(v, off, 64);
    part[l] = v;
  }
  __shared__ float red[4][Ln];
  const int lane = t & 63, wv = t >> 6;
  if (lane == 0) {
#pragma unroll
    for (int l = 0; l < Ln; ++l) red[wv][l] = part[l];
  }
  __syncthreads();
  if (t < Ln)
    xq[t*En + j] = red[0][t] + red[1][t] + red[2][t] + red[3][t];
}

// ---------------- Kernel 1: KV projection (bf16 MFMA) + fused RoPE on K ----------------
// KV[m][n] = sum_e spike[m][e] * Wkv[n][e], n<128 -> K (RoPE'd), n>=128 -> V
// 128x128 tile, BK=32, 256 threads (4 waves, each 64x64), mfma_f32_16x16x32_bf16
__global__ __launch_bounds__(256)
void kvproj_kernel(const float* __restrict__ spike, const int* __restrict__ offsets,
                   const float* __restrict__ cosT, const float* __restrict__ sinT,
                   const float* __restrict__ Wk, const float* __restrict__ Wv,
                   __hip_bfloat16* __restrict__ KV)
{
  // 128 rows x 40 bf16 (=20 uints, 80B: 16B-aligned rows, 2-way-free bank pattern)
  __shared__ __align__(16) uint32_t As[128*20];
  __shared__ __align__(16) uint32_t Bs[128*20];
  const int t = threadIdx.x;
  const int mtile = blockIdx.x >> 1;     // adjacent pair shares A-tile -> L2/LLC locality
  const int ntile = blockIdx.x & 1;      // 0 -> K (Wk), 1 -> V (Wv)
  const int m0 = mtile * 128;
  const float* __restrict__ Wb = ntile ? Wv : Wk;

  const int lane = t & 63;
  const int wv = t >> 6;
  const int quad = lane >> 4;
  const int lr = lane & 15;
  const int wm = wv >> 1, wn = wv & 1;

  f32x4 acc[4][4];
#pragma unroll
  for (int i=0;i<4;i++)
#pragma unroll
    for (int j=0;j<4;j++) acc[i][j] = (f32x4){0.f,0.f,0.f,0.f};

  const int srow = t >> 3;   // 0..31
  const int scg  = t & 7;    // 4-float chunk within the 32-wide k-slab
  const float* ga = spike + (size_t)(m0 + srow)*En + scg*4;
  const float* gb = Wb    + (size_t)srow*En + scg*4;

  for (int k0 = 0; k0 < En; k0 += 32) {
#pragma unroll
    for (int i = 0; i < 4; ++i) {
      float4 v = *(const float4*)(ga + (size_t)(32*i)*En + k0);
      uint2 pa; pa.x = pack_bf16(v.x, v.y); pa.y = pack_bf16(v.z, v.w);
      *(uint2*)&As[(srow + 32*i)*20 + scg*2] = pa;
      float4 w = *(const float4*)(gb + (size_t)(32*i)*En + k0);
      uint2 pb; pb.x = pack_bf16(w.x, w.y); pb.y = pack_bf16(w.z, w.w);
      *(uint2*)&Bs[(srow + 32*i)*20 + scg*2] = pb;
    }
    __syncthreads();
    bf16x8 aF[4], bF[4];
#pragma unroll
    for (int mi=0;mi<4;mi++) aF[mi] = *(const bf16x8*)&As[(wm*64 + mi*16 + lr)*20 + quad*4];
#pragma unroll
    for (int ni=0;ni<4;ni++) bF[ni] = *(const bf16x8*)&Bs[(wn*64 + ni*16 + lr)*20 + quad*4];
#pragma unroll
    for (int mi=0;mi<4;mi++)
#pragma unroll
      for (int ni=0;ni<4;ni++)
        acc[mi][ni] = __builtin_amdgcn_mfma_f32_16x16x32_bf16(aF[mi], bF[ni], acc[mi][ni], 0, 0, 0);
    __syncthreads();
  }

  // Epilogue. C/D layout: col n = lane&15 (within 16-tile), row m = quad*4 + reg.
  if (ntile == 0) {
    // K half: RoPE. Within a wave, d = n&63 = ni*16+lr; kvh = wn. Partner d^32 -> ni^2, same lane.
#pragma unroll
    for (int mi=0;mi<4;mi++) {
#pragma unroll
      for (int r=0;r<4;r++) {
        const int m = m0 + wm*64 + mi*16 + quad*4 + r;
        const int off = offsets[m];
#pragma unroll
        for (int ni=0;ni<4;ni++) {
          const int d = ni*16 + lr;
          const float v = acc[mi][ni][r];
          const float p = acc[mi][ni^2][r];
          const float rot = (ni < 2) ? -p : p;      // d<32: -x[d+32]; d>=32: +x[d-32]
          const float c = cosT[off*Dn + d];
          const float s = sinT[off*Dn + d];
          KV[(size_t)m*256 + wn*64 + d] = __float2bfloat16(v*c + rot*s);
        }
      }
    }
  } else {
#pragma unroll
    for (int mi=0;mi<4;mi++)
#pragma unroll
      for (int r=0;r<4;r++) {
        const int m = m0 + wm*64 + mi*16 + quad*4 + r;
#pragma unroll
        for (int ni=0;ni<4;ni++)
          KV[(size_t)m*256 + 128 + wn*64 + ni*16 + lr] = __float2bfloat16(acc[mi][ni][r]);
      }
  }
}

// ---------------- Kernel 2: attention, one block per (b*k, h) ----------------
__global__ __launch_bounds__(256)
void attn_kernel(const float* __restrict__ xq, const __hip_bfloat16* __restrict__ KVb,
                 const int* __restrict__ lengths, float* __restrict__ attn_out)
{
  __shared__ __align__(16) float Q[Ln*Dn];
  __shared__ __align__(16) float P[Ln*528];   // stride 528: 2-way-free banks
  __shared__ float sums[Ln];

  const int bk = blockIdx.x >> 3;
  const int h  = blockIdx.x & 7;
  const int kvh = h >> 2;                     // interleaved repeat_kv: h // n_rep
  const int len = lengths[bk];
  const int t = threadIdx.x;

  {
    const int idx = t * 4;
    const int l = idx >> 6, d = idx & 63;
    *(float4*)&Q[idx] = *(const float4*)&xq[l*En + h*Dn + d];
  }
  __syncthreads();

  const int l = t >> 4;
  const int scol = t & 15;
  const uint16_t* __restrict__ KV = (const uint16_t*)KVb;
  const uint16_t* Kbase = KV + (size_t)bk*Sn*256 + kvh*64;

  float q[64];
#pragma unroll
  for (int d=0; d<64; ++d) q[d] = Q[l*Dn + d];

  float sc[32];
  float mloc = -3.0e38f;
#pragma unroll 4
  for (int i=0;i<32;i++) {
    const int s = scol + 16*i;
    float v = -3.0e38f;
    if (s < len) {
      const uint16_t* kr = Kbase + (size_t)s*256;
      float dot = 0.f;
#pragma unroll
      for (int dg=0; dg<8; ++dg) {
        uint4 kw = *(const uint4*)(kr + dg*8);
        dot += blo(kw.x)*q[dg*8+0] + bhi(kw.x)*q[dg*8+1]
             + blo(kw.y)*q[dg*8+2] + bhi(kw.y)*q[dg*8+3]
             + blo(kw.z)*q[dg*8+4] + bhi(kw.z)*q[dg*8+5]
             + blo(kw.w)*q[dg*8+6] + bhi(kw.w)*q[dg*8+7];
      }
      v = dot * 0.125f;   // 1/sqrt(64)
    }
    sc[i] = v;
    mloc = fmaxf(mloc, v);
  }
  // row softmax across the 16 lanes sharing l (len>=1 so max is finite)
#pragma unroll
  for (int o=1;o<16;o<<=1) mloc = fmaxf(mloc, __shfl_xor(mloc, o, 16));
  float ssum = 0.f;
#pragma unroll
  for (int i=0;i<32;i++) { float p = __expf(sc[i]-mloc); sc[i]=p; ssum += p; }
#pragma unroll
  for (int o=1;o<16;o<<=1) ssum += __shfl_xor(ssum, o, 16);
#pragma unroll
  for (int i=0;i<32;i++) P[l*528 + scol + 16*i] = sc[i];
  if (scol == 0) sums[l] = ssum;
  __syncthreads();

  // PV: thread (l, dq) accumulates O[l][dq*4 .. +3]; P==0 beyond len
  const int dq = t & 15;
  const uint16_t* Vb = KV + (size_t)bk*Sn*256 + 128 + kvh*64 + dq*4;
  float4 o4 = {0.f,0.f,0.f,0.f};
  const int len4 = (len + 3) & ~3;
  for (int s=0; s<len4; s+=4) {
    float4 p4 = *(const float4*)&P[l*528 + s];
    uint2 v0 = *(const uint2*)(Vb + (size_t)(s+0)*256);
    uint2 v1 = *(const uint2*)(Vb + (size_t)(s+1)*256);
    uint2 v2 = *(const uint2*)(Vb + (size_t)(s+2)*256);
    uint2 v3 = *(const uint2*)(Vb + (size_t)(s+3)*256);
    o4.x += p4.x*blo(v0.x) + p4.y*blo(v1.x) + p4.z*blo(v2.x) + p4.w*blo(v3.x);
    o4.y += p4.x*bhi(v0.x) + p4.y*bhi(v1.x) + p4.z*bhi(v2.x) + p4.w*bhi(v3.x);
    o4.z += p4.x*blo(v0.y) + p4.y*blo(v1.y) + p4.z*blo(v2.y) + p4.w*blo(v3.y);
    o4.w += p4.x*bhi(v0.y) + p4.y*bhi(v1.y) + p4.z*bhi(v2.y) + p4.w*bhi(v3.y);
  }
  const float rs = 1.0f / sums[l];
  float4 outv; outv.x = o4.x*rs; outv.y = o4.y*rs; outv.z = o4.z*rs; outv.w = o4.w*rs;
  *(float4*)&attn_out[((size_t)bk*Ln + l)*(Hn*Dn) + h*Dn + dq*4] = outv;
}

// ---------------- Kernel 3: out = attn_out(4096x512) @ Wo^T ----------------
__global__ __launch_bounds__(256)
void oproj_kernel(const float* __restrict__ A, const float* __restrict__ Wo,
                  float* __restrict__ out)
{
  __shared__ __align__(16) float As[64*36];
  __shared__ __align__(16) float Bs[64*36];
  const int t = threadIdx.x;
  const int r0 = (blockIdx.x >> 3) * 64;
  const int e0 = (blockIdx.x & 7) * 64;
  const int ty = t >> 4, tx = t & 15;
  float acc[4][4];
#pragma unroll
  for (int i=0;i<4;i++)
#pragma unroll
    for (int j=0;j<4;j++) acc[i][j] = 0.f;

  const int srow = t >> 3, scg = t & 7;
  for (int k0=0;k0<512;k0+=32) {
#pragma unroll
    for (int i=0;i<2;i++) {
      const int row = srow + 32*i;
      *(float4*)&As[row*36 + scg*4] = *(const float4*)&A [(size_t)(r0+row)*512 + k0 + scg*4];
      *(float4*)&Bs[row*36 + scg*4] = *(const float4*)&Wo[(size_t)(e0+row)*512 + k0 + scg*4];
    }
    __syncthreads();
#pragma unroll
    for (int kk=0;kk<32;kk+=4) {
      float4 av[4], bv[4];
#pragma unroll
      for (int i=0;i<4;i++) av[i] = *(const float4*)&As[(ty+16*i)*36 + kk];
#pragma unroll
      for (int j=0;j<4;j++) bv[j] = *(const float4*)&Bs[(tx+16*j)*36 + kk];
#pragma unroll
      for (int i=0;i<4;i++)
#pragma unroll
        for (int j=0;j<4;j++)
          acc[i][j] += av[i].x*bv[j].x + av[i].y*bv[j].y + av[i].z*bv[j].z + av[i].w*bv[j].w;
    }
    __syncthreads();
  }
#pragma unroll
  for (int i=0;i<4;i++)
#pragma unroll
    for (int j=0;j<4;j++)
      out[(size_t)(r0+ty+16*i)*512 + e0 + tx + 16*j] = acc[i][j];
}

// ---------------- launch ----------------
extern "C" void kernel_launch(void* const* d_in, const int* in_sizes, int n_in,
                              void* d_out, int out_size, void* d_ws, size_t ws_size,
                              hipStream_t stream)
{
  const float* spike   = (const float*)d_in[0];
  const int*   offsets = (const int*)d_in[1];
  const int*   lengths = (const int*)d_in[2];
  const float* cosT    = (const float*)d_in[3];
  const float* sinT    = (const float*)d_in[4];
  const float* latent  = (const float*)d_in[5];
  const float* Wq      = (const float*)d_in[6];
  const float* Wk      = (const float*)d_in[7];
  const float* Wv      = (const float*)d_in[8];
  const float* Wo      = (const float*)d_in[9];
  float* out = (float*)d_out;

  char* ws = (char*)d_ws;
  float* xq = (float*)ws;                                        // 32 KB
  __hip_bfloat16* KV = (__hip_bfloat16*)(ws + 65536);            // 64 MB (131072 x 256 bf16)
  float* attn_out = (float*)(ws + 65536 + (size_t)MTOT*256*2);   // 8 MB (4096 x 512 f32)

  hipLaunchKernelGGL(xq_kernel,     dim3(512),  dim3(256), 0, stream, latent, Wq, xq);
  hipLaunchKernelGGL(kvproj_kernel, dim3(2048), dim3(256), 0, stream, spike, offsets, cosT, sinT, Wk, Wv, KV);
  hipLaunchKernelGGL(attn_kernel,   dim3(2048), dim3(256), 0, stream, xq, KV, lengths, attn_out);
  hipLaunchKernelGGL(oproj_kernel,  dim3(512),  dim3(256), 0, stream, attn_out, Wo, out);
}

// Round 2
// 496.901 us; speedup vs baseline: 1.5122x; 1.5122x over previous
//
#include <hip/hip_runtime.h>
#include <hip/hip_bf16.h>
#include <stdint.h>

typedef __attribute__((ext_vector_type(8))) short bf16x8;
typedef __attribute__((ext_vector_type(4))) float f32x4;

union FragU { uint4 u; bf16x8 v; };

#define Bn 16
#define Kn 16
#define Sn 512
#define En 512
#define Ln 16
#define Hn 8
#define Dn 64
#define BKTOT 256            // B*K
#define MTOT (BKTOT*Sn)      // 131072 spike rows

__device__ __forceinline__ uint32_t pack_bf16(float lo, float hi) {
  uint32_t a = __float_as_uint(lo) + 0x8000u;
  uint32_t b = __float_as_uint(hi) + 0x8000u;
  return __builtin_amdgcn_perm(b, a, 0x07060302u);  // [b.hi16 : a.hi16]
}
__device__ __forceinline__ uint16_t bf16_1(float x) {
  __hip_bfloat16 h = __float2bfloat16(x);
  return *(uint16_t*)&h;
}

// ---------------- Kernel 0: xq = latent_query @ Wq^T  (16 x 512) ----------------
__global__ __launch_bounds__(256)
void xq_kernel(const float* __restrict__ latent, const float* __restrict__ Wq,
               float* __restrict__ xq)
{
  const int j = blockIdx.x;
  const int t = threadIdx.x;
  const float w0 = Wq[j*En + t];
  const float w1 = Wq[j*En + t + 256];
  float part[Ln];
#pragma unroll
  for (int l = 0; l < Ln; ++l)
    part[l] = w0 * latent[l*En + t] + w1 * latent[l*En + t + 256];
#pragma unroll
  for (int l = 0; l < Ln; ++l) {
    float v = part[l];
#pragma unroll
    for (int off = 32; off > 0; off >>= 1) v += __shfl_down(v, off, 64);
    part[l] = v;
  }
  __shared__ float red[4][Ln];
  const int lane = t & 63, wv = t >> 6;
  if (lane == 0) {
#pragma unroll
    for (int l = 0; l < Ln; ++l) red[wv][l] = part[l];
  }
  __syncthreads();
  if (t < Ln)
    xq[t*En + j] = red[0][t] + red[1][t] + red[2][t] + red[3][t];
}

// ---------------- Kernel 1: KV projection, one block = 64m x 256n (K|V fused) ----------------
// Writes K row-major [bk][s][128] (RoPE'd) and V transposed Vt[bk][n'][s] (n' = kvh*64+d).
__global__ __launch_bounds__(256)
void kvproj_kernel(const float* __restrict__ spike, const int* __restrict__ offsets,
                   const float* __restrict__ cosT, const float* __restrict__ sinT,
                   const float* __restrict__ Wk, const float* __restrict__ Wv,
                   uint16_t* __restrict__ Kbuf, uint16_t* __restrict__ Vt)
{
  __shared__ __align__(16) uint32_t As[64*20];    // 64 rows x 40 bf16 (pad: 2-way-free)
  __shared__ __align__(16) uint32_t Bs[256*20];   // 256 rows (Wk 0..127 | Wv 128..255)
  const int t = threadIdx.x;
  const int m0 = blockIdx.x * 64;
  const int lane = t & 63, wv = t >> 6;
  const int quad = lane >> 4, lr = lane & 15;

  f32x4 acc[4][4];
#pragma unroll
  for (int i=0;i<4;i++)
#pragma unroll
    for (int j=0;j<4;j++) acc[i][j] = (f32x4){0.f,0.f,0.f,0.f};

  const int srow = t >> 3;   // 0..31
  const int scg  = t & 7;

  for (int k0 = 0; k0 < En; k0 += 32) {
#pragma unroll
    for (int i = 0; i < 2; ++i) {
      const int row = srow + 32*i;
      float4 v = *(const float4*)&spike[(size_t)(m0 + row)*En + k0 + scg*4];
      uint2 p; p.x = pack_bf16(v.x, v.y); p.y = pack_bf16(v.z, v.w);
      *(uint2*)&As[row*20 + scg*2] = p;
    }
#pragma unroll
    for (int i = 0; i < 8; ++i) {
      const int row = srow + 32*i;
      const float* src = (i < 4) ? &Wk[(size_t)row*En] : &Wv[(size_t)(row-128)*En];
      float4 v = *(const float4*)&src[k0 + scg*4];
      uint2 p; p.x = pack_bf16(v.x, v.y); p.y = pack_bf16(v.z, v.w);
      *(uint2*)&Bs[row*20 + scg*2] = p;
    }
    __syncthreads();
    FragU aF[4], bF[4];
#pragma unroll
    for (int mi=0;mi<4;mi++) aF[mi].u = *(const uint4*)&As[(mi*16+lr)*20 + quad*4];
#pragma unroll
    for (int ni=0;ni<4;ni++) bF[ni].u = *(const uint4*)&Bs[(wv*64 + ni*16 + lr)*20 + quad*4];
#pragma unroll
    for (int mi=0;mi<4;mi++)
#pragma unroll
      for (int ni=0;ni<4;ni++)
        acc[mi][ni] = __builtin_amdgcn_mfma_f32_16x16x32_bf16(aF[mi].v, bF[ni].v, acc[mi][ni], 0,0,0);
    __syncthreads();
  }

  const int bk = m0 >> 9;
  const int sbase = m0 & 511;
  if (wv < 2) {
    // K half: kvh = wv, d = ni*16+lr; RoPE partner d^32 -> ni^2 (same lane)
#pragma unroll
    for (int mi=0;mi<4;mi++) {
#pragma unroll
      for (int r=0;r<4;r++) {
        const int s = sbase + mi*16 + quad*4 + r;
        const int off = offsets[m0 + mi*16 + quad*4 + r];
#pragma unroll
        for (int ni=0;ni<4;ni++) {
          const int d = ni*16 + lr;
          const float v = acc[mi][ni][r];
          const float p = acc[mi][ni^2][r];
          const float rot = (ni < 2) ? -p : p;
          const float c  = cosT[off*Dn + d];
          const float sn = sinT[off*Dn + d];
          Kbuf[((size_t)(bk*512 + s))*128 + wv*64 + d] = bf16_1(v*c + rot*sn);
        }
      }
    }
  } else {
    const int nbase = (wv - 2) * 64;
#pragma unroll
    for (int mi=0;mi<4;mi++) {
#pragma unroll
      for (int ni=0;ni<4;ni++) {
        const int np = nbase + ni*16 + lr;
        const int s  = sbase + mi*16 + quad*4;
        uint2 pk;
        pk.x = pack_bf16(acc[mi][ni][0], acc[mi][ni][1]);
        pk.y = pack_bf16(acc[mi][ni][2], acc[mi][ni][3]);
        *(uint2*)&Vt[((size_t)(bk*128 + np))*512 + s] = pk;
      }
    }
  }
}

// ---------------- Kernel 2: flash attention, one block per (bk, kvh), wave = head ----------------
__global__ __launch_bounds__(256)
void attn_kernel(const float* __restrict__ xq, const uint16_t* __restrict__ Kbuf,
                 const uint16_t* __restrict__ Vt, const int* __restrict__ lengths,
                 float* __restrict__ attn_out)
{
  __shared__ __align__(16) uint16_t Ks [128*72];   // K chunk: 128 s x 64 d (pad 72)
  __shared__ __align__(16) uint16_t Vts[64*136];   // V^T chunk: 64 d x 128 s (pad 136)
  __shared__ __align__(16) uint16_t Ps [4*16*136]; // per-wave P: 16 l x 128 s (pad 136)

  const int t = threadIdx.x;
  const int bk = blockIdx.x >> 1, kvh = blockIdx.x & 1;
  const int w = t >> 6, lane = t & 63;
  const int quad = lane >> 4, lr = lane & 15;
  const int h = kvh*4 + w;
  const int len = lengths[bk];

  // Q A-fragments, pre-scaled by 1/sqrt(D)=0.125 (exact, pow2)
  FragU aQ[2];
#pragma unroll
  for (int kk=0;kk<2;kk++) {
    const float* qp = &xq[lr*En + h*Dn + kk*32 + quad*8];
    float4 q0 = *(const float4*)qp;
    float4 q1 = *(const float4*)(qp + 4);
    aQ[kk].u.x = pack_bf16(q0.x*0.125f, q0.y*0.125f);
    aQ[kk].u.y = pack_bf16(q0.z*0.125f, q0.w*0.125f);
    aQ[kk].u.z = pack_bf16(q1.x*0.125f, q1.y*0.125f);
    aQ[kk].u.w = pack_bf16(q1.z*0.125f, q1.w*0.125f);
  }

  float m_run[4], l_run[4], alpha[4];
  f32x4 oacc[4];
#pragma unroll
  for (int r=0;r<4;r++){ m_run[r] = -3.0e38f; l_run[r] = 0.f; }
#pragma unroll
  for (int nd=0;nd<4;nd++) oacc[nd] = (f32x4){0.f,0.f,0.f,0.f};

  const int krow = t >> 1, kseg = t & 1;   // K stage: 2 threads/row, 32 bf16 each
  const int vrow = t >> 2, vseg = t & 3;   // V stage: 4 threads/row, 32 bf16 each

  for (int c = 0; c < 4; ++c) {
    const int s0 = c * 128;
    if (s0 >= len) break;                  // len uniform per block
    __syncthreads();                       // protect prev chunk readers
    {
      const uint16_t* g = &Kbuf[((size_t)(bk*512 + s0 + krow))*128 + kvh*64 + kseg*32];
      uint16_t* dst = &Ks[krow*72 + kseg*32];
      uint4 a0 = *(const uint4*)g, a1 = *(const uint4*)(g+8);
      uint4 a2 = *(const uint4*)(g+16), a3 = *(const uint4*)(g+24);
      *(uint4*)dst = a0; *(uint4*)(dst+8) = a1; *(uint4*)(dst+16) = a2; *(uint4*)(dst+24) = a3;

      const uint16_t* gv = &Vt[((size_t)(bk*128 + kvh*64 + vrow))*512 + s0 + vseg*32];
      uint16_t* dv = &Vts[vrow*136 + vseg*32];
      uint4 b0 = *(const uint4*)gv, b1 = *(const uint4*)(gv+8);
      uint4 b2 = *(const uint4*)(gv+16), b3 = *(const uint4*)(gv+24);
      *(uint4*)dv = b0; *(uint4*)(dv+8) = b1; *(uint4*)(dv+16) = b2; *(uint4*)(dv+24) = b3;
    }
    __syncthreads();

    // QK^T: 8 s-tiles of 16
    f32x4 sc[8];
#pragma unroll
    for (int ni=0;ni<8;ni++) {
      FragU b0, b1;
      b0.u = *(const uint4*)&Ks[(ni*16+lr)*72 + quad*8];
      b1.u = *(const uint4*)&Ks[(ni*16+lr)*72 + 32 + quad*8];
      f32x4 a = (f32x4){0.f,0.f,0.f,0.f};
      a = __builtin_amdgcn_mfma_f32_16x16x32_bf16(aQ[0].v, b0.v, a, 0,0,0);
      a = __builtin_amdgcn_mfma_f32_16x16x32_bf16(aQ[1].v, b1.v, a, 0,0,0);
      sc[ni] = a;
    }
    // ragged mask (col = s0 + ni*16 + lr for all 4 rows of this lane)
#pragma unroll
    for (int ni=0;ni<8;ni++)
      if (s0 + ni*16 + lr >= len)
        sc[ni] = (f32x4){-3.0e38f,-3.0e38f,-3.0e38f,-3.0e38f};

    // online softmax, rows l = quad*4 + r live across the 16 lanes of a quad
#pragma unroll
    for (int r=0;r<4;r++) {
      float mx = sc[0][r];
#pragma unroll
      for (int ni=1;ni<8;ni++) mx = fmaxf(mx, sc[ni][r]);
#pragma unroll
      for (int o=1;o<16;o<<=1) mx = fmaxf(mx, __shfl_xor(mx, o, 16));
      const float mnew = fmaxf(m_run[r], mx);
      alpha[r] = __expf(m_run[r] - mnew);
      m_run[r] = mnew;
      float ssum = 0.f;
#pragma unroll
      for (int ni=0;ni<8;ni++) {
        float p = __expf(sc[ni][r] - mnew);
        sc[ni][r] = p;
        ssum += p;
      }
#pragma unroll
      for (int o=1;o<16;o<<=1) ssum += __shfl_xor(ssum, o, 16);
      l_run[r] = l_run[r]*alpha[r] + ssum;
    }

    // P -> LDS (C-layout store), becomes A-layout on reload
#pragma unroll
    for (int ni=0;ni<8;ni++)
#pragma unroll
      for (int r=0;r<4;r++)
        Ps[(w*16 + quad*4 + r)*136 + ni*16 + lr] = bf16_1(sc[ni][r]);

#pragma unroll
    for (int nd=0;nd<4;nd++)
#pragma unroll
      for (int r=0;r<4;r++) oacc[nd][r] *= alpha[r];

    // PV: A = P (16 x 128), B = V^T (64 x 128), accumulate out 16 x 64
#pragma unroll
    for (int kk=0;kk<4;kk++) {
      FragU aP;
      aP.u = *(const uint4*)&Ps[(w*16 + lr)*136 + kk*32 + quad*8];
#pragma unroll
      for (int nd=0;nd<4;nd++) {
        FragU bV;
        bV.u = *(const uint4*)&Vts[(nd*16+lr)*136 + kk*32 + quad*8];
        oacc[nd] = __builtin_amdgcn_mfma_f32_16x16x32_bf16(aP.v, bV.v, oacc[nd], 0,0,0);
      }
    }
  }

#pragma unroll
  for (int r=0;r<4;r++) {
    const float rs = 1.0f / l_run[r];
    const int l = quad*4 + r;
#pragma unroll
    for (int nd=0;nd<4;nd++)
      attn_out[((size_t)(bk*16 + l))*512 + h*64 + nd*16 + lr] = oacc[nd][r] * rs;
  }
}

// ---------------- Kernel 3: out = attn_out(4096x512) @ Wo^T ----------------
__global__ __launch_bounds__(256)
void oproj_kernel(const float* __restrict__ A, const float* __restrict__ Wo,
                  float* __restrict__ out)
{
  __shared__ __align__(16) float As[64*36];
  __shared__ __align__(16) float Bs[64*36];
  const int t = threadIdx.x;
  const int r0 = (blockIdx.x >> 3) * 64;
  const int e0 = (blockIdx.x & 7) * 64;
  const int ty = t >> 4, tx = t & 15;
  float acc[4][4];
#pragma unroll
  for (int i=0;i<4;i++)
#pragma unroll
    for (int j=0;j<4;j++) acc[i][j] = 0.f;

  const int srow = t >> 3, scg = t & 7;
  for (int k0=0;k0<512;k0+=32) {
#pragma unroll
    for (int i=0;i<2;i++) {
      const int row = srow + 32*i;
      *(float4*)&As[row*36 + scg*4] = *(const float4*)&A [(size_t)(r0+row)*512 + k0 + scg*4];
      *(float4*)&Bs[row*36 + scg*4] = *(const float4*)&Wo[(size_t)(e0+row)*512 + k0 + scg*4];
    }
    __syncthreads();
#pragma unroll
    for (int kk=0;kk<32;kk+=4) {
      float4 av[4], bv[4];
#pragma unroll
      for (int i=0;i<4;i++) av[i] = *(const float4*)&As[(ty+16*i)*36 + kk];
#pragma unroll
      for (int j=0;j<4;j++) bv[j] = *(const float4*)&Bs[(tx+16*j)*36 + kk];
#pragma unroll
      for (int i=0;i<4;i++)
#pragma unroll
        for (int j=0;j<4;j++)
          acc[i][j] += av[i].x*bv[j].x + av[i].y*bv[j].y + av[i].z*bv[j].z + av[i].w*bv[j].w;
    }
    __syncthreads();
  }
#pragma unroll
  for (int i=0;i<4;i++)
#pragma unroll
    for (int j=0;j<4;j++)
      out[(size_t)(r0+ty+16*i)*512 + e0 + tx + 16*j] = acc[i][j];
}

// ---------------- launch ----------------
extern "C" void kernel_launch(void* const* d_in, const int* in_sizes, int n_in,
                              void* d_out, int out_size, void* d_ws, size_t ws_size,
                              hipStream_t stream)
{
  const float* spike   = (const float*)d_in[0];
  const int*   offsets = (const int*)d_in[1];
  const int*   lengths = (const int*)d_in[2];
  const float* cosT    = (const float*)d_in[3];
  const float* sinT    = (const float*)d_in[4];
  const float* latent  = (const float*)d_in[5];
  const float* Wq      = (const float*)d_in[6];
  const float* Wk      = (const float*)d_in[7];
  const float* Wv      = (const float*)d_in[8];
  const float* Wo      = (const float*)d_in[9];
  float* out = (float*)d_out;

  char* ws = (char*)d_ws;
  float*    xq   = (float*)ws;                                   // 32 KB (reserve 64 KB)
  uint16_t* Kbuf = (uint16_t*)(ws + 65536);                      // 32 MB: [bk][s][128]
  uint16_t* Vt   = (uint16_t*)(ws + 65536 + (33554432ull));      // 32 MB: [bk][n'][s]
  float* attn_out = (float*)(ws + 65536 + 67108864ull);          // 8 MB

  hipLaunchKernelGGL(xq_kernel,     dim3(512),  dim3(256), 0, stream, latent, Wq, xq);
  hipLaunchKernelGGL(kvproj_kernel, dim3(2048), dim3(256), 0, stream, spike, offsets, cosT, sinT, Wk, Wv, Kbuf, Vt);
  hipLaunchKernelGGL(attn_kernel,   dim3(512),  dim3(256), 0, stream, xq, Kbuf, Vt, lengths, attn_out);
  hipLaunchKernelGGL(oproj_kernel,  dim3(512),  dim3(256), 0, stream, attn_out, Wo, out);
}

// Round 3
// 436.375 us; speedup vs baseline: 1.7219x; 1.1387x over previous
//
#include <hip/hip_runtime.h>
#include <hip/hip_bf16.h>
#include <stdint.h>

typedef __attribute__((ext_vector_type(8))) short bf16x8;
typedef __attribute__((ext_vector_type(4))) float f32x4;

union FragU { uint4 u; bf16x8 v; };

#define Bn 16
#define Kn 16
#define Sn 512
#define En 512
#define Ln 16
#define Hn 8
#define Dn 64
#define BKTOT 256
#define MTOT (BKTOT*Sn)

__device__ __forceinline__ uint32_t pack_bf16(float lo, float hi) {
  uint32_t a = __float_as_uint(lo) + 0x8000u;
  uint32_t b = __float_as_uint(hi) + 0x8000u;
  return __builtin_amdgcn_perm(b, a, 0x07060302u);  // [b.hi16 : a.hi16]
}
__device__ __forceinline__ uint16_t bf16_1(float x) {
  __hip_bfloat16 h = __float2bfloat16(x);
  return *(uint16_t*)&h;
}
__device__ __forceinline__ void gload_lds16(const void* g, void* l) {
  __builtin_amdgcn_global_load_lds(
      (const __attribute__((address_space(1))) uint32_t*)g,
      (__attribute__((address_space(3))) uint32_t*)l, 16, 0, 0);
}

// ---------------- Kernel 0: xq = latent_query @ Wq^T  (16 x 512) ----------------
__global__ __launch_bounds__(256)
void xq_kernel(const float* __restrict__ latent, const float* __restrict__ Wq,
               float* __restrict__ xq)
{
  const int j = blockIdx.x;
  const int t = threadIdx.x;
  const float w0 = Wq[j*En + t];
  const float w1 = Wq[j*En + t + 256];
  float part[Ln];
#pragma unroll
  for (int l = 0; l < Ln; ++l)
    part[l] = w0 * latent[l*En + t] + w1 * latent[l*En + t + 256];
#pragma unroll
  for (int l = 0; l < Ln; ++l) {
    float v = part[l];
#pragma unroll
    for (int off = 32; off > 0; off >>= 1) v += __shfl_down(v, off, 64);
    part[l] = v;
  }
  __shared__ float red[4][Ln];
  const int lane = t & 63, wv = t >> 6;
  if (lane == 0) {
#pragma unroll
    for (int l = 0; l < Ln; ++l) red[wv][l] = part[l];
  }
  __syncthreads();
  if (t < Ln)
    xq[t*En + j] = red[0][t] + red[1][t] + red[2][t] + red[3][t];
}

// ---------------- Kernel 0b: weight conversion ----------------
// Wsw[kb][n][p] (uint4 chunks of 8 bf16): chunk p holds W[n][kb*64 + (p^(n&7))*8 .. +8]
// (XOR swizzle baked in so kvproj's unpadded LDS fragment reads are 2-way = free).
// Wob: plain row-major bf16 of Wo (512x512).
__global__ __launch_bounds__(256)
void wconv_kernel(const float* __restrict__ Wk, const float* __restrict__ Wv,
                  const float* __restrict__ Wo,
                  uint4* __restrict__ Wsw, uint4* __restrict__ Wob)
{
  const int t = threadIdx.x;
  const int b = blockIdx.x;
  if (b < 64) {
    const int idx = b*256 + t;           // chunk id, 16384 total
    const int kb = idx >> 11;
    const int rem = idx & 2047;
    const int n = rem >> 3, p = rem & 7;
    const int c = p ^ (n & 7);
    const float* src = (n < 128 ? Wk + (size_t)n*En : Wv + (size_t)(n-128)*En) + kb*64 + c*8;
    float4 v0 = *(const float4*)src;
    float4 v1 = *(const float4*)(src+4);
    uint4 o;
    o.x = pack_bf16(v0.x,v0.y); o.y = pack_bf16(v0.z,v0.w);
    o.z = pack_bf16(v1.x,v1.y); o.w = pack_bf16(v1.z,v1.w);
    Wsw[idx] = o;
  } else {
    const int idx = (b-64)*256 + t;      // 0..32767
    const float* src = Wo + (size_t)idx*8;
    float4 v0 = *(const float4*)src;
    float4 v1 = *(const float4*)(src+4);
    uint4 o;
    o.x = pack_bf16(v0.x,v0.y); o.y = pack_bf16(v0.z,v0.w);
    o.z = pack_bf16(v1.x,v1.y); o.w = pack_bf16(v1.z,v1.w);
    Wob[idx] = o;
  }
}

// ---------------- Kernel 1: KV projection, 64m x 256n, BK=64, async B staging ----------------
__global__ __launch_bounds__(256)
void kvproj_kernel(const float* __restrict__ spike, const int* __restrict__ offsets,
                   const float* __restrict__ cosT, const float* __restrict__ sinT,
                   const uint4* __restrict__ Wsw,
                   uint16_t* __restrict__ Kbuf, uint16_t* __restrict__ Vt)
{
  __shared__ __align__(16) uint16_t Bs[256*64];   // 32 KB, swizzled rows (64 bf16, no pad)
  __shared__ __align__(16) uint16_t As[64*72];    // 9 KB, rows 64 bf16 + 8 pad
  const int t = threadIdx.x;
  const int m0 = blockIdx.x * 64;
  const int lane = t & 63, wv = t >> 6;
  const int quad = lane >> 4, lr = lane & 15;

  f32x4 acc[4][4];
#pragma unroll
  for (int i=0;i<4;i++)
#pragma unroll
    for (int j=0;j<4;j++) acc[i][j] = (f32x4){0.f,0.f,0.f,0.f};

  const int arow = t >> 3;   // 0..31
  const int aseg = t & 7;

  for (int kb = 0; kb < 8; ++kb) {
    // B: 32 KB direct-to-LDS (wave-uniform base + lane*16)
    const char* gb = (const char*)(Wsw + kb*2048) + (wv*64 + lane)*16;
    char* lb = (char*)Bs + wv*1024;
#pragma unroll
    for (int i = 0; i < 8; ++i)
      gload_lds16(gb + i*4096, lb + i*4096);
    // A: f32 -> bf16 pack, 2 reps
#pragma unroll
    for (int j = 0; j < 2; ++j) {
      const int row = arow + 32*j;
      const float* src = &spike[(size_t)(m0+row)*En + kb*64 + aseg*8];
      float4 v0 = *(const float4*)src;
      float4 v1 = *(const float4*)(src+4);
      uint4 o;
      o.x = pack_bf16(v0.x,v0.y); o.y = pack_bf16(v0.z,v0.w);
      o.z = pack_bf16(v1.x,v1.y); o.w = pack_bf16(v1.z,v1.w);
      *(uint4*)&As[row*72 + aseg*8] = o;
    }
    __syncthreads();
#pragma unroll
    for (int kk = 0; kk < 2; ++kk) {
      const int c = kk*4 + quad;
      FragU aF[4], bF[4];
#pragma unroll
      for (int mi=0;mi<4;mi++) aF[mi].u = *(const uint4*)&As[(mi*16+lr)*72 + c*8];
#pragma unroll
      for (int ni=0;ni<4;ni++) {
        const int n = wv*64 + ni*16 + lr;
        bF[ni].u = *(const uint4*)&Bs[n*64 + (c ^ (n&7))*8];
      }
#pragma unroll
      for (int mi=0;mi<4;mi++)
#pragma unroll
        for (int ni=0;ni<4;ni++)
          acc[mi][ni] = __builtin_amdgcn_mfma_f32_16x16x32_bf16(aF[mi].v, bF[ni].v, acc[mi][ni], 0,0,0);
    }
    __syncthreads();
  }

  const int bk = m0 >> 9;
  const int sbase = m0 & 511;
  if (wv < 2) {
    // K half: kvh = wv, d = ni*16+lr; RoPE partner d^32 -> ni^2 (same lane)
#pragma unroll
    for (int mi=0;mi<4;mi++) {
#pragma unroll
      for (int r=0;r<4;r++) {
        const int s = sbase + mi*16 + quad*4 + r;
        const int off = offsets[m0 + mi*16 + quad*4 + r];
#pragma unroll
        for (int ni=0;ni<4;ni++) {
          const int d = ni*16 + lr;
          const float v = acc[mi][ni][r];
          const float p = acc[mi][ni^2][r];
          const float rot = (ni < 2) ? -p : p;
          const float cc  = cosT[off*Dn + d];
          const float sn  = sinT[off*Dn + d];
          Kbuf[((size_t)(bk*512 + s))*128 + wv*64 + d] = bf16_1(v*cc + rot*sn);
        }
      }
    }
  } else {
    const int nbase = (wv - 2) * 64;
#pragma unroll
    for (int mi=0;mi<4;mi++) {
#pragma unroll
      for (int ni=0;ni<4;ni++) {
        const int np = nbase + ni*16 + lr;
        const int s  = sbase + mi*16 + quad*4;
        uint2 pk;
        pk.x = pack_bf16(acc[mi][ni][0], acc[mi][ni][1]);
        pk.y = pack_bf16(acc[mi][ni][2], acc[mi][ni][3]);
        *(uint2*)&Vt[((size_t)(bk*128 + np))*512 + s] = pk;
      }
    }
  }
}

// ---------------- Kernel 2: flash attention, one block per (bk, kvh), wave = head ----------------
__global__ __launch_bounds__(256)
void attn_kernel(const float* __restrict__ xq, const uint16_t* __restrict__ Kbuf,
                 const uint16_t* __restrict__ Vt, const int* __restrict__ lengths,
                 uint16_t* __restrict__ attn_out)
{
  __shared__ __align__(16) uint16_t Ks [128*72];
  __shared__ __align__(16) uint16_t Vts[64*136];
  __shared__ __align__(16) uint16_t Ps [4*16*136];

  const int t = threadIdx.x;
  const int bk = blockIdx.x >> 1, kvh = blockIdx.x & 1;
  const int w = t >> 6, lane = t & 63;
  const int quad = lane >> 4, lr = lane & 15;
  const int h = kvh*4 + w;
  const int len = lengths[bk];

  FragU aQ[2];
#pragma unroll
  for (int kk=0;kk<2;kk++) {
    const float* qp = &xq[lr*En + h*Dn + kk*32 + quad*8];
    float4 q0 = *(const float4*)qp;
    float4 q1 = *(const float4*)(qp + 4);
    aQ[kk].u.x = pack_bf16(q0.x*0.125f, q0.y*0.125f);
    aQ[kk].u.y = pack_bf16(q0.z*0.125f, q0.w*0.125f);
    aQ[kk].u.z = pack_bf16(q1.x*0.125f, q1.y*0.125f);
    aQ[kk].u.w = pack_bf16(q1.z*0.125f, q1.w*0.125f);
  }

  float m_run[4], l_run[4], alpha[4];
  f32x4 oacc[4];
#pragma unroll
  for (int r=0;r<4;r++){ m_run[r] = -3.0e38f; l_run[r] = 0.f; }
#pragma unroll
  for (int nd=0;nd<4;nd++) oacc[nd] = (f32x4){0.f,0.f,0.f,0.f};

  const int krow = t >> 1, kseg = t & 1;
  const int vrow = t >> 2, vseg = t & 3;

  for (int c = 0; c < 4; ++c) {
    const int s0 = c * 128;
    if (s0 >= len) break;
    __syncthreads();
    {
      const uint16_t* g = &Kbuf[((size_t)(bk*512 + s0 + krow))*128 + kvh*64 + kseg*32];
      uint16_t* dst = &Ks[krow*72 + kseg*32];
      uint4 a0 = *(const uint4*)g, a1 = *(const uint4*)(g+8);
      uint4 a2 = *(const uint4*)(g+16), a3 = *(const uint4*)(g+24);
      *(uint4*)dst = a0; *(uint4*)(dst+8) = a1; *(uint4*)(dst+16) = a2; *(uint4*)(dst+24) = a3;

      const uint16_t* gv = &Vt[((size_t)(bk*128 + kvh*64 + vrow))*512 + s0 + vseg*32];
      uint16_t* dv = &Vts[vrow*136 + vseg*32];
      uint4 b0 = *(const uint4*)gv, b1 = *(const uint4*)(gv+8);
      uint4 b2 = *(const uint4*)(gv+16), b3 = *(const uint4*)(gv+24);
      *(uint4*)dv = b0; *(uint4*)(dv+8) = b1; *(uint4*)(dv+16) = b2; *(uint4*)(dv+24) = b3;
    }
    __syncthreads();

    f32x4 sc[8];
#pragma unroll
    for (int ni=0;ni<8;ni++) {
      FragU b0, b1;
      b0.u = *(const uint4*)&Ks[(ni*16+lr)*72 + quad*8];
      b1.u = *(const uint4*)&Ks[(ni*16+lr)*72 + 32 + quad*8];
      f32x4 a = (f32x4){0.f,0.f,0.f,0.f};
      a = __builtin_amdgcn_mfma_f32_16x16x32_bf16(aQ[0].v, b0.v, a, 0,0,0);
      a = __builtin_amdgcn_mfma_f32_16x16x32_bf16(aQ[1].v, b1.v, a, 0,0,0);
      sc[ni] = a;
    }
#pragma unroll
    for (int ni=0;ni<8;ni++)
      if (s0 + ni*16 + lr >= len)
        sc[ni] = (f32x4){-3.0e38f,-3.0e38f,-3.0e38f,-3.0e38f};

#pragma unroll
    for (int r=0;r<4;r++) {
      float mx = sc[0][r];
#pragma unroll
      for (int ni=1;ni<8;ni++) mx = fmaxf(mx, sc[ni][r]);
#pragma unroll
      for (int o=1;o<16;o<<=1) mx = fmaxf(mx, __shfl_xor(mx, o, 16));
      const float mnew = fmaxf(m_run[r], mx);
      alpha[r] = __expf(m_run[r] - mnew);
      m_run[r] = mnew;
      float ssum = 0.f;
#pragma unroll
      for (int ni=0;ni<8;ni++) {
        float p = __expf(sc[ni][r] - mnew);
        sc[ni][r] = p;
        ssum += p;
      }
#pragma unroll
      for (int o=1;o<16;o<<=1) ssum += __shfl_xor(ssum, o, 16);
      l_run[r] = l_run[r]*alpha[r] + ssum;
    }

#pragma unroll
    for (int ni=0;ni<8;ni++)
#pragma unroll
      for (int r=0;r<4;r++)
        Ps[(w*16 + quad*4 + r)*136 + ni*16 + lr] = bf16_1(sc[ni][r]);

#pragma unroll
    for (int nd=0;nd<4;nd++)
#pragma unroll
      for (int r=0;r<4;r++) oacc[nd][r] *= alpha[r];

#pragma unroll
    for (int kk=0;kk<4;kk++) {
      FragU aP;
      aP.u = *(const uint4*)&Ps[(w*16 + lr)*136 + kk*32 + quad*8];
#pragma unroll
      for (int nd=0;nd<4;nd++) {
        FragU bV;
        bV.u = *(const uint4*)&Vts[(nd*16+lr)*136 + kk*32 + quad*8];
        oacc[nd] = __builtin_amdgcn_mfma_f32_16x16x32_bf16(aP.v, bV.v, oacc[nd], 0,0,0);
      }
    }
  }

#pragma unroll
  for (int r=0;r<4;r++) {
    const float rs = 1.0f / l_run[r];
    const int l = quad*4 + r;
#pragma unroll
    for (int nd=0;nd<4;nd++)
      attn_out[((size_t)(bk*16 + l))*512 + h*64 + nd*16 + lr] = bf16_1(oacc[nd][r] * rs);
  }
}

// ---------------- Kernel 3: out = attn_out(4096x512,bf16) @ Wob^T (bf16 MFMA) ----------------
__global__ __launch_bounds__(256)
void oproj_kernel(const uint16_t* __restrict__ Ab, const uint16_t* __restrict__ Wob,
                  float* __restrict__ out)
{
  __shared__ __align__(16) uint16_t As[128*72];
  __shared__ __align__(16) uint16_t Bs[128*72];
  const int t = threadIdx.x;
  const int m0 = (blockIdx.x >> 2) * 128;
  const int n0 = (blockIdx.x & 3) * 128;
  const int lane = t & 63, wv = t >> 6;
  const int quad = lane >> 4, lr = lane & 15;
  const int wm = wv >> 1, wn = wv & 1;

  f32x4 acc[4][4];
#pragma unroll
  for (int i=0;i<4;i++)
#pragma unroll
    for (int j=0;j<4;j++) acc[i][j] = (f32x4){0.f,0.f,0.f,0.f};

  const int srow = t >> 3, sseg = t & 7;
  for (int kb = 0; kb < 8; ++kb) {
#pragma unroll
    for (int j = 0; j < 4; ++j) {
      const int row = srow + 32*j;
      *(uint4*)&As[row*72 + sseg*8] = *(const uint4*)&Ab [(size_t)(m0+row)*512 + kb*64 + sseg*8];
      *(uint4*)&Bs[row*72 + sseg*8] = *(const uint4*)&Wob[(size_t)(n0+row)*512 + kb*64 + sseg*8];
    }
    __syncthreads();
#pragma unroll
    for (int kk = 0; kk < 2; ++kk) {
      const int c = kk*4 + quad;
      FragU aF[4], bF[4];
#pragma unroll
      for (int mi=0;mi<4;mi++) aF[mi].u = *(const uint4*)&As[(wm*64+mi*16+lr)*72 + c*8];
#pragma unroll
      for (int ni=0;ni<4;ni++) bF[ni].u = *(const uint4*)&Bs[(wn*64+ni*16+lr)*72 + c*8];
#pragma unroll
      for (int mi=0;mi<4;mi++)
#pragma unroll
        for (int ni=0;ni<4;ni++)
          acc[mi][ni] = __builtin_amdgcn_mfma_f32_16x16x32_bf16(aF[mi].v, bF[ni].v, acc[mi][ni], 0,0,0);
    }
    __syncthreads();
  }
#pragma unroll
  for (int mi=0;mi<4;mi++)
#pragma unroll
    for (int r=0;r<4;r++)
#pragma unroll
      for (int ni=0;ni<4;ni++)
        out[(size_t)(m0 + wm*64 + mi*16 + quad*4 + r)*512 + n0 + wn*64 + ni*16 + lr] = acc[mi][ni][r];
}

// ---------------- launch ----------------
extern "C" void kernel_launch(void* const* d_in, const int* in_sizes, int n_in,
                              void* d_out, int out_size, void* d_ws, size_t ws_size,
                              hipStream_t stream)
{
  const float* spike   = (const float*)d_in[0];
  const int*   offsets = (const int*)d_in[1];
  const int*   lengths = (const int*)d_in[2];
  const float* cosT    = (const float*)d_in[3];
  const float* sinT    = (const float*)d_in[4];
  const float* latent  = (const float*)d_in[5];
  const float* Wq      = (const float*)d_in[6];
  const float* Wk      = (const float*)d_in[7];
  const float* Wv      = (const float*)d_in[8];
  const float* Wo      = (const float*)d_in[9];
  float* out = (float*)d_out;

  char* ws = (char*)d_ws;
  float*    xq   = (float*)ws;                            // 64 KB reserved
  uint4*    Wsw  = (uint4*)(ws + 65536);                  // 256 KB
  uint4*    Wob  = (uint4*)(ws + 65536 + 262144);         // 512 KB
  uint16_t* Kbuf = (uint16_t*)(ws + 1048576);             // 32 MB
  uint16_t* Vt   = (uint16_t*)(ws + 1048576 + 33554432ull);   // 32 MB
  uint16_t* attn_out = (uint16_t*)(ws + 1048576 + 67108864ull); // 4 MB

  hipLaunchKernelGGL(xq_kernel,     dim3(512),  dim3(256), 0, stream, latent, Wq, xq);
  hipLaunchKernelGGL(wconv_kernel,  dim3(192),  dim3(256), 0, stream, Wk, Wv, Wo, Wsw, Wob);
  hipLaunchKernelGGL(kvproj_kernel, dim3(2048), dim3(256), 0, stream, spike, offsets, cosT, sinT, Wsw, Kbuf, Vt);
  hipLaunchKernelGGL(attn_kernel,   dim3(512),  dim3(256), 0, stream, xq, Kbuf, Vt, lengths, attn_out);
  hipLaunchKernelGGL(oproj_kernel,  dim3(128),  dim3(256), 0, stream, attn_out, (const uint16_t*)Wob, out);
}

// Round 4
// 430.796 us; speedup vs baseline: 1.7442x; 1.0130x over previous
//
#include <hip/hip_runtime.h>
#include <hip/hip_bf16.h>
#include <stdint.h>

typedef __attribute__((ext_vector_type(8))) short bf16x8;
typedef __attribute__((ext_vector_type(4))) float f32x4;

union FragU { uint4 u; bf16x8 v; };

#define Bn 16
#define Kn 16
#define Sn 512
#define En 512
#define Ln 16
#define Hn 8
#define Dn 64
#define BKTOT 256
#define MTOT (BKTOT*Sn)

__device__ __forceinline__ uint32_t pack_bf16(float lo, float hi) {
  uint32_t a = __float_as_uint(lo) + 0x8000u;
  uint32_t b = __float_as_uint(hi) + 0x8000u;
  return __builtin_amdgcn_perm(b, a, 0x07060302u);  // [b.hi16 : a.hi16]
}
__device__ __forceinline__ uint16_t bf16_1(float x) {
  __hip_bfloat16 h = __float2bfloat16(x);
  return *(uint16_t*)&h;
}
__device__ __forceinline__ void gload_lds16(const void* g, void* l) {
  __builtin_amdgcn_global_load_lds(
      (const __attribute__((address_space(1))) uint32_t*)g,
      (__attribute__((address_space(3))) uint32_t*)l, 16, 0, 0);
}

// ---------------- Kernel 0: xq = latent_query @ Wq^T  (16 x 512) ----------------
__global__ __launch_bounds__(256)
void xq_kernel(const float* __restrict__ latent, const float* __restrict__ Wq,
               float* __restrict__ xq)
{
  const int j = blockIdx.x;
  const int t = threadIdx.x;
  const float w0 = Wq[j*En + t];
  const float w1 = Wq[j*En + t + 256];
  float part[Ln];
#pragma unroll
  for (int l = 0; l < Ln; ++l)
    part[l] = w0 * latent[l*En + t] + w1 * latent[l*En + t + 256];
#pragma unroll
  for (int l = 0; l < Ln; ++l) {
    float v = part[l];
#pragma unroll
    for (int off = 32; off > 0; off >>= 1) v += __shfl_down(v, off, 64);
    part[l] = v;
  }
  __shared__ float red[4][Ln];
  const int lane = t & 63, wv = t >> 6;
  if (lane == 0) {
#pragma unroll
    for (int l = 0; l < Ln; ++l) red[wv][l] = part[l];
  }
  __syncthreads();
  if (t < Ln)
    xq[t*En + j] = red[0][t] + red[1][t] + red[2][t] + red[3][t];
}

// ---------------- Kernel 0b: weight conversion ----------------
// Wsw[kb][n][p]: chunk p holds W[n][kb*64 + (p^(n&7))*8 .. +8] (XOR bank swizzle baked in).
// Wob: plain row-major bf16 of Wo (512x512).
__global__ __launch_bounds__(256)
void wconv_kernel(const float* __restrict__ Wk, const float* __restrict__ Wv,
                  const float* __restrict__ Wo,
                  uint4* __restrict__ Wsw, uint4* __restrict__ Wob)
{
  const int t = threadIdx.x;
  const int b = blockIdx.x;
  if (b < 64) {
    const int idx = b*256 + t;
    const int kb = idx >> 11;
    const int rem = idx & 2047;
    const int n = rem >> 3, p = rem & 7;
    const int c = p ^ (n & 7);
    const float* src = (n < 128 ? Wk + (size_t)n*En : Wv + (size_t)(n-128)*En) + kb*64 + c*8;
    float4 v0 = *(const float4*)src;
    float4 v1 = *(const float4*)(src+4);
    uint4 o;
    o.x = pack_bf16(v0.x,v0.y); o.y = pack_bf16(v0.z,v0.w);
    o.z = pack_bf16(v1.x,v1.y); o.w = pack_bf16(v1.z,v1.w);
    Wsw[idx] = o;
  } else {
    const int idx = (b-64)*256 + t;
    const float* src = Wo + (size_t)idx*8;
    float4 v0 = *(const float4*)src;
    float4 v1 = *(const float4*)(src+4);
    uint4 o;
    o.x = pack_bf16(v0.x,v0.y); o.y = pack_bf16(v0.z,v0.w);
    o.z = pack_bf16(v1.x,v1.y); o.w = pack_bf16(v1.z,v1.w);
    Wob[idx] = o;
  }
}

// ---------------- Kernel 1: KV projection, 64m x 256n, BK=64, ragged early-exit ----------------
__global__ __launch_bounds__(256)
void kvproj_kernel(const float* __restrict__ spike, const int* __restrict__ offsets,
                   const float* __restrict__ cosT, const float* __restrict__ sinT,
                   const uint4* __restrict__ Wsw, const int* __restrict__ lengths,
                   uint16_t* __restrict__ Kbuf, uint16_t* __restrict__ Vt)
{
  __shared__ __align__(16) uint16_t Bs[256*64];   // 32 KB, swizzled rows
  __shared__ __align__(16) uint16_t As[64*72];    // 9 KB, rows 64 bf16 + 8 pad
  const int t = threadIdx.x;
  const int bk   = blockIdx.x >> 3;
  const int tile = blockIdx.x & 7;
  // Ragged skip: rows s >= len are never read downstream (scores masked, P=0).
  if (tile * 64 >= lengths[bk]) return;
  const int m0 = blockIdx.x * 64;
  const int lane = t & 63, wv = t >> 6;
  const int quad = lane >> 4, lr = lane & 15;

  f32x4 acc[4][4];
#pragma unroll
  for (int i=0;i<4;i++)
#pragma unroll
    for (int j=0;j<4;j++) acc[i][j] = (f32x4){0.f,0.f,0.f,0.f};

  const int arow = t >> 3;
  const int aseg = t & 7;

  for (int kb = 0; kb < 8; ++kb) {
    const char* gb = (const char*)(Wsw + kb*2048) + (wv*64 + lane)*16;
    char* lb = (char*)Bs + wv*1024;
#pragma unroll
    for (int i = 0; i < 8; ++i)
      gload_lds16(gb + i*4096, lb + i*4096);
#pragma unroll
    for (int j = 0; j < 2; ++j) {
      const int row = arow + 32*j;
      const float* src = &spike[(size_t)(m0+row)*En + kb*64 + aseg*8];
      float4 v0 = *(const float4*)src;
      float4 v1 = *(const float4*)(src+4);
      uint4 o;
      o.x = pack_bf16(v0.x,v0.y); o.y = pack_bf16(v0.z,v0.w);
      o.z = pack_bf16(v1.x,v1.y); o.w = pack_bf16(v1.z,v1.w);
      *(uint4*)&As[row*72 + aseg*8] = o;
    }
    __syncthreads();
#pragma unroll
    for (int kk = 0; kk < 2; ++kk) {
      const int c = kk*4 + quad;
      FragU aF[4], bF[4];
#pragma unroll
      for (int mi=0;mi<4;mi++) aF[mi].u = *(const uint4*)&As[(mi*16+lr)*72 + c*8];
#pragma unroll
      for (int ni=0;ni<4;ni++) {
        const int n = wv*64 + ni*16 + lr;
        bF[ni].u = *(const uint4*)&Bs[n*64 + (c ^ (n&7))*8];
      }
#pragma unroll
      for (int mi=0;mi<4;mi++)
#pragma unroll
        for (int ni=0;ni<4;ni++)
          acc[mi][ni] = __builtin_amdgcn_mfma_f32_16x16x32_bf16(aF[mi].v, bF[ni].v, acc[mi][ni], 0,0,0);
    }
    __syncthreads();
  }

  const int sbase = m0 & 511;
  if (wv < 2) {
#pragma unroll
    for (int mi=0;mi<4;mi++) {
#pragma unroll
      for (int r=0;r<4;r++) {
        const int s = sbase + mi*16 + quad*4 + r;
        const int off = offsets[m0 + mi*16 + quad*4 + r];
#pragma unroll
        for (int ni=0;ni<4;ni++) {
          const int d = ni*16 + lr;
          const float v = acc[mi][ni][r];
          const float p = acc[mi][ni^2][r];
          const float rot = (ni < 2) ? -p : p;
          const float cc  = cosT[off*Dn + d];
          const float sn  = sinT[off*Dn + d];
          Kbuf[((size_t)(bk*512 + s))*128 + wv*64 + d] = bf16_1(v*cc + rot*sn);
        }
      }
    }
  } else {
    const int nbase = (wv - 2) * 64;
#pragma unroll
    for (int mi=0;mi<4;mi++) {
#pragma unroll
      for (int ni=0;ni<4;ni++) {
        const int np = nbase + ni*16 + lr;
        const int s  = sbase + mi*16 + quad*4;
        uint2 pk;
        pk.x = pack_bf16(acc[mi][ni][0], acc[mi][ni][1]);
        pk.y = pack_bf16(acc[mi][ni][2], acc[mi][ni][3]);
        *(uint2*)&Vt[((size_t)(bk*128 + np))*512 + s] = pk;
      }
    }
  }
}

// ---------------- Kernel 2: flash attention, one block per (bk, kvh), wave = head ----------------
__global__ __launch_bounds__(256)
void attn_kernel(const float* __restrict__ xq, const uint16_t* __restrict__ Kbuf,
                 const uint16_t* __restrict__ Vt, const int* __restrict__ lengths,
                 uint16_t* __restrict__ attn_out)
{
  __shared__ __align__(16) uint16_t Ks [128*72];
  __shared__ __align__(16) uint16_t Vts[64*136];
  __shared__ __align__(16) uint16_t Ps [4*16*136];

  const int t = threadIdx.x;
  const int bk = blockIdx.x >> 1, kvh = blockIdx.x & 1;
  const int w = t >> 6, lane = t & 63;
  const int quad = lane >> 4, lr = lane & 15;
  const int h = kvh*4 + w;
  const int len = lengths[bk];

  FragU aQ[2];
#pragma unroll
  for (int kk=0;kk<2;kk++) {
    const float* qp = &xq[lr*En + h*Dn + kk*32 + quad*8];
    float4 q0 = *(const float4*)qp;
    float4 q1 = *(const float4*)(qp + 4);
    aQ[kk].u.x = pack_bf16(q0.x*0.125f, q0.y*0.125f);
    aQ[kk].u.y = pack_bf16(q0.z*0.125f, q0.w*0.125f);
    aQ[kk].u.z = pack_bf16(q1.x*0.125f, q1.y*0.125f);
    aQ[kk].u.w = pack_bf16(q1.z*0.125f, q1.w*0.125f);
  }

  float m_run[4], l_run[4], alpha[4];
  f32x4 oacc[4];
#pragma unroll
  for (int r=0;r<4;r++){ m_run[r] = -3.0e38f; l_run[r] = 0.f; }
#pragma unroll
  for (int nd=0;nd<4;nd++) oacc[nd] = (f32x4){0.f,0.f,0.f,0.f};

  const int krow = t >> 1, kseg = t & 1;
  const int vrow = t >> 2, vseg = t & 3;

  for (int c = 0; c < 4; ++c) {
    const int s0 = c * 128;
    if (s0 >= len) break;
    __syncthreads();
    {
      const uint16_t* g = &Kbuf[((size_t)(bk*512 + s0 + krow))*128 + kvh*64 + kseg*32];
      uint16_t* dst = &Ks[krow*72 + kseg*32];
      uint4 a0 = *(const uint4*)g, a1 = *(const uint4*)(g+8);
      uint4 a2 = *(const uint4*)(g+16), a3 = *(const uint4*)(g+24);
      *(uint4*)dst = a0; *(uint4*)(dst+8) = a1; *(uint4*)(dst+16) = a2; *(uint4*)(dst+24) = a3;

      const uint16_t* gv = &Vt[((size_t)(bk*128 + kvh*64 + vrow))*512 + s0 + vseg*32];
      uint16_t* dv = &Vts[vrow*136 + vseg*32];
      uint4 b0 = *(const uint4*)gv, b1 = *(const uint4*)(gv+8);
      uint4 b2 = *(const uint4*)(gv+16), b3 = *(const uint4*)(gv+24);
      *(uint4*)dv = b0; *(uint4*)(dv+8) = b1; *(uint4*)(dv+16) = b2; *(uint4*)(dv+24) = b3;
    }
    __syncthreads();

    f32x4 sc[8];
#pragma unroll
    for (int ni=0;ni<8;ni++) {
      FragU b0, b1;
      b0.u = *(const uint4*)&Ks[(ni*16+lr)*72 + quad*8];
      b1.u = *(const uint4*)&Ks[(ni*16+lr)*72 + 32 + quad*8];
      f32x4 a = (f32x4){0.f,0.f,0.f,0.f};
      a = __builtin_amdgcn_mfma_f32_16x16x32_bf16(aQ[0].v, b0.v, a, 0,0,0);
      a = __builtin_amdgcn_mfma_f32_16x16x32_bf16(aQ[1].v, b1.v, a, 0,0,0);
      sc[ni] = a;
    }
#pragma unroll
    for (int ni=0;ni<8;ni++)
      if (s0 + ni*16 + lr >= len)
        sc[ni] = (f32x4){-3.0e38f,-3.0e38f,-3.0e38f,-3.0e38f};

#pragma unroll
    for (int r=0;r<4;r++) {
      float mx = sc[0][r];
#pragma unroll
      for (int ni=1;ni<8;ni++) mx = fmaxf(mx, sc[ni][r]);
#pragma unroll
      for (int o=1;o<16;o<<=1) mx = fmaxf(mx, __shfl_xor(mx, o, 16));
      const float mnew = fmaxf(m_run[r], mx);
      alpha[r] = __expf(m_run[r] - mnew);
      m_run[r] = mnew;
      float ssum = 0.f;
#pragma unroll
      for (int ni=0;ni<8;ni++) {
        float p = __expf(sc[ni][r] - mnew);
        sc[ni][r] = p;
        ssum += p;
      }
#pragma unroll
      for (int o=1;o<16;o<<=1) ssum += __shfl_xor(ssum, o, 16);
      l_run[r] = l_run[r]*alpha[r] + ssum;
    }

#pragma unroll
    for (int ni=0;ni<8;ni++)
#pragma unroll
      for (int r=0;r<4;r++)
        Ps[(w*16 + quad*4 + r)*136 + ni*16 + lr] = bf16_1(sc[ni][r]);

#pragma unroll
    for (int nd=0;nd<4;nd++)
#pragma unroll
      for (int r=0;r<4;r++) oacc[nd][r] *= alpha[r];

#pragma unroll
    for (int kk=0;kk<4;kk++) {
      FragU aP;
      aP.u = *(const uint4*)&Ps[(w*16 + lr)*136 + kk*32 + quad*8];
#pragma unroll
      for (int nd=0;nd<4;nd++) {
        FragU bV;
        bV.u = *(const uint4*)&Vts[(nd*16+lr)*136 + kk*32 + quad*8];
        oacc[nd] = __builtin_amdgcn_mfma_f32_16x16x32_bf16(aP.v, bV.v, oacc[nd], 0,0,0);
      }
    }
  }

#pragma unroll
  for (int r=0;r<4;r++) {
    const float rs = 1.0f / l_run[r];
    const int l = quad*4 + r;
#pragma unroll
    for (int nd=0;nd<4;nd++)
      attn_out[((size_t)(bk*16 + l))*512 + h*64 + nd*16 + lr] = bf16_1(oacc[nd][r] * rs);
  }
}

// ---------------- Kernel 3: out = attn_out(4096x512,bf16) @ Wob^T (bf16 MFMA) ----------------
__global__ __launch_bounds__(256)
void oproj_kernel(const uint16_t* __restrict__ Ab, const uint16_t* __restrict__ Wob,
                  float* __restrict__ out)
{
  __shared__ __align__(16) uint16_t As[128*72];
  __shared__ __align__(16) uint16_t Bs[128*72];
  const int t = threadIdx.x;
  const int m0 = (blockIdx.x >> 2) * 128;
  const int n0 = (blockIdx.x & 3) * 128;
  const int lane = t & 63, wv = t >> 6;
  const int quad = lane >> 4, lr = lane & 15;
  const int wm = wv >> 1, wn = wv & 1;

  f32x4 acc[4][4];
#pragma unroll
  for (int i=0;i<4;i++)
#pragma unroll
    for (int j=0;j<4;j++) acc[i][j] = (f32x4){0.f,0.f,0.f,0.f};

  const int srow = t >> 3, sseg = t & 7;
  for (int kb = 0; kb < 8; ++kb) {
#pragma unroll
    for (int j = 0; j < 4; ++j) {
      const int row = srow + 32*j;
      *(uint4*)&As[row*72 + sseg*8] = *(const uint4*)&Ab [(size_t)(m0+row)*512 + kb*64 + sseg*8];
      *(uint4*)&Bs[row*72 + sseg*8] = *(const uint4*)&Wob[(size_t)(n0+row)*512 + kb*64 + sseg*8];
    }
    __syncthreads();
#pragma unroll
    for (int kk = 0; kk < 2; ++kk) {
      const int c = kk*4 + quad;
      FragU aF[4], bF[4];
#pragma unroll
      for (int mi=0;mi<4;mi++) aF[mi].u = *(const uint4*)&As[(wm*64+mi*16+lr)*72 + c*8];
#pragma unroll
      for (int ni=0;ni<4;ni++) bF[ni].u = *(const uint4*)&Bs[(wn*64+ni*16+lr)*72 + c*8];
#pragma unroll
      for (int mi=0;mi<4;mi++)
#pragma unroll
        for (int ni=0;ni<4;ni++)
          acc[mi][ni] = __builtin_amdgcn_mfma_f32_16x16x32_bf16(aF[mi].v, bF[ni].v, acc[mi][ni], 0,0,0);
    }
    __syncthreads();
  }
#pragma unroll
  for (int mi=0;mi<4;mi++)
#pragma unroll
    for (int r=0;r<4;r++)
#pragma unroll
      for (int ni=0;ni<4;ni++)
        out[(size_t)(m0 + wm*64 + mi*16 + quad*4 + r)*512 + n0 + wn*64 + ni*16 + lr] = acc[mi][ni][r];
}

// ---------------- launch ----------------
extern "C" void kernel_launch(void* const* d_in, const int* in_sizes, int n_in,
                              void* d_out, int out_size, void* d_ws, size_t ws_size,
                              hipStream_t stream)
{
  const float* spike   = (const float*)d_in[0];
  const int*   offsets = (const int*)d_in[1];
  const int*   lengths = (const int*)d_in[2];
  const float* cosT    = (const float*)d_in[3];
  const float* sinT    = (const float*)d_in[4];
  const float* latent  = (const float*)d_in[5];
  const float* Wq      = (const float*)d_in[6];
  const float* Wk      = (const float*)d_in[7];
  const float* Wv      = (const float*)d_in[8];
  const float* Wo      = (const float*)d_in[9];
  float* out = (float*)d_out;

  char* ws = (char*)d_ws;
  float*    xq   = (float*)ws;                                  // 64 KB reserved
  uint4*    Wsw  = (uint4*)(ws + 65536);                        // 256 KB
  uint4*    Wob  = (uint4*)(ws + 65536 + 262144);               // 512 KB
  uint16_t* Kbuf = (uint16_t*)(ws + 1048576);                   // 32 MB
  uint16_t* Vt   = (uint16_t*)(ws + 1048576 + 33554432ull);     // 32 MB
  uint16_t* attn_out = (uint16_t*)(ws + 1048576 + 67108864ull); // 4 MB

  hipLaunchKernelGGL(xq_kernel,     dim3(512),  dim3(256), 0, stream, latent, Wq, xq);
  hipLaunchKernelGGL(wconv_kernel,  dim3(192),  dim3(256), 0, stream, Wk, Wv, Wo, Wsw, Wob);
  hipLaunchKernelGGL(kvproj_kernel, dim3(2048), dim3(256), 0, stream, spike, offsets, cosT, sinT, Wsw, lengths, Kbuf, Vt);
  hipLaunchKernelGGL(attn_kernel,   dim3(512),  dim3(256), 0, stream, xq, Kbuf, Vt, lengths, attn_out);
  hipLaunchKernelGGL(oproj_kernel,  dim3(128),  dim3(256), 0, stream, attn_out, (const uint16_t*)Wob, out);
}